// Round 1
// baseline (267.117 us; speedup 1.0000x reference)
//
#include <hip/hip_runtime.h>
#include <math.h>

// Problem constants
constexpr int Bb = 8;     // batch
constexpr int Ns = 1024;  // tokens (32x32)
constexpr int Es = 256;   // embed
constexpr int NH = 8;     // heads
constexpr int DH = 32;    // head dim
constexpr int Mrows = Bb * Ns;  // 8192

// GEMM tiling
#define BM 64
#define BN 64
#define BK 32
#define LDT 68   // padded stride (floats) for transposed LDS tiles; keeps 16B align

// C = A[M,K] @ W[Ncol,K]^T + bias, K = 256.
// MODE 0: QKV epilogue -> scatter (q*scale, k, v) into [B][H][N][DH] buffers.
// MODE 1: proj epilogue -> o0[row*Es + col].
template<int MODE>
__global__ __launch_bounds__(256)
void gemm_nt(const float* __restrict__ A, const float* __restrict__ W,
             const float* __restrict__ bias,
             float* __restrict__ o0, float* __restrict__ o1, float* __restrict__ o2)
{
    __shared__ float AsT[BK][LDT];
    __shared__ float WsT[BK][LDT];
    const int K = Es;
    int t = threadIdx.x;
    int m0 = blockIdx.x * BM;
    int j0 = blockIdx.y * BN;
    int ty = t >> 4, tx = t & 15;
    int lrow = t >> 3;          // 0..31
    int lc = (t & 7) << 2;      // 0,4,..,28
    float acc[4][4] = {};
    for (int k0 = 0; k0 < K; k0 += BK) {
        float4 a0 = *(const float4*)(A + (size_t)(m0 + lrow) * K + k0 + lc);
        float4 a1 = *(const float4*)(A + (size_t)(m0 + lrow + 32) * K + k0 + lc);
        float4 w0 = *(const float4*)(W + (size_t)(j0 + lrow) * K + k0 + lc);
        float4 w1 = *(const float4*)(W + (size_t)(j0 + lrow + 32) * K + k0 + lc);
        __syncthreads();  // protect previous iteration's LDS reads
        AsT[lc+0][lrow] = a0.x; AsT[lc+1][lrow] = a0.y;
        AsT[lc+2][lrow] = a0.z; AsT[lc+3][lrow] = a0.w;
        AsT[lc+0][lrow+32] = a1.x; AsT[lc+1][lrow+32] = a1.y;
        AsT[lc+2][lrow+32] = a1.z; AsT[lc+3][lrow+32] = a1.w;
        WsT[lc+0][lrow] = w0.x; WsT[lc+1][lrow] = w0.y;
        WsT[lc+2][lrow] = w0.z; WsT[lc+3][lrow] = w0.w;
        WsT[lc+0][lrow+32] = w1.x; WsT[lc+1][lrow+32] = w1.y;
        WsT[lc+2][lrow+32] = w1.z; WsT[lc+3][lrow+32] = w1.w;
        __syncthreads();
        #pragma unroll
        for (int kk = 0; kk < BK; kk++) {
            float4 ar = *(const float4*)&AsT[kk][ty << 2];  // ds_read_b128
            float4 wr = *(const float4*)&WsT[kk][tx << 2];
            float av[4] = {ar.x, ar.y, ar.z, ar.w};
            float wv[4] = {wr.x, wr.y, wr.z, wr.w};
            #pragma unroll
            for (int i = 0; i < 4; i++)
                #pragma unroll
                for (int j = 0; j < 4; j++)
                    acc[i][j] = fmaf(av[i], wv[j], acc[i][j]);
        }
    }
    #pragma unroll
    for (int i = 0; i < 4; i++) {
        int row = m0 + (ty << 2) + i;
        #pragma unroll
        for (int j = 0; j < 4; j++) {
            int col = j0 + (tx << 2) + j;
            float val = acc[i][j] + bias[col];
            if (MODE == 0) {
                int part = col >> 8;           // 0:q 1:k 2:v
                int head = (col >> 5) & 7;
                int d = col & 31;
                int b = row >> 10;
                int n = row & 1023;
                size_t idx = (((size_t)(b * NH + head)) * Ns + n) * DH + d;
                if (part == 0)      o0[idx] = val * 0.0625f;  // scale = E^-0.5
                else if (part == 1) o1[idx] = val;
                else                o2[idx] = val;
            } else {
                o0[(size_t)row * Es + col] = val;
            }
        }
    }
}

// One thread per (b, h, query token): online softmax over <=7x11 window.
__global__ __launch_bounds__(256)
void attn_win(const float* __restrict__ q, const float* __restrict__ k,
              const float* __restrict__ v, float* __restrict__ out)
{
    int t = blockIdx.x * 256 + threadIdx.x;   // 0..65535
    int n = t & (Ns - 1);
    int bh = t >> 10;                          // b*NH + h
    int h = bh & (NH - 1);
    int b = bh >> 3;
    int hq = n >> 5, wq = n & 31;

    const float4* qp = (const float4*)(q + ((size_t)bh * Ns + n) * DH);
    float4 qr[8];
    #pragma unroll
    for (int i = 0; i < 8; i++) qr[i] = qp[i];

    float mrun = -INFINITY, l = 0.f;
    float4 acc[8];
    #pragma unroll
    for (int i = 0; i < 8; i++) acc[i] = make_float4(0.f, 0.f, 0.f, 0.f);

    int h0 = hq - 3; if (h0 < 0) h0 = 0;
    int h1 = hq + 3; if (h1 > 31) h1 = 31;
    int w0 = wq - 5; if (w0 < 0) w0 = 0;
    int w1 = wq + 5; if (w1 > 31) w1 = 31;

    for (int hh = h0; hh <= h1; hh++) {
        for (int ww = w0; ww <= w1; ww++) {
            int nn = (hh << 5) + ww;
            const float4* kp = (const float4*)(k + ((size_t)bh * Ns + nn) * DH);
            float s = 0.f;
            #pragma unroll
            for (int i = 0; i < 8; i++) {
                float4 kv = kp[i];
                s = fmaf(qr[i].x, kv.x, s); s = fmaf(qr[i].y, kv.y, s);
                s = fmaf(qr[i].z, kv.z, s); s = fmaf(qr[i].w, kv.w, s);
            }
            float mn = fmaxf(mrun, s);
            float alpha = __expf(mrun - mn);   // exp(-inf)=0 on first iter
            float p = __expf(s - mn);
            l = l * alpha + p;
            const float4* vp = (const float4*)(v + ((size_t)bh * Ns + nn) * DH);
            #pragma unroll
            for (int i = 0; i < 8; i++) {
                float4 vv = vp[i];
                acc[i].x = fmaf(acc[i].x, alpha, p * vv.x);
                acc[i].y = fmaf(acc[i].y, alpha, p * vv.y);
                acc[i].z = fmaf(acc[i].z, alpha, p * vv.z);
                acc[i].w = fmaf(acc[i].w, alpha, p * vv.w);
            }
            mrun = mn;
        }
    }
    float inv = 1.f / l;
    float4* op = (float4*)(out + ((size_t)(b * Ns + n)) * Es + h * DH);
    #pragma unroll
    for (int i = 0; i < 8; i++) {
        float4 o = acc[i];
        o.x *= inv; o.y *= inv; o.z *= inv; o.w *= inv;
        op[i] = o;
    }
}

extern "C" void kernel_launch(void* const* d_in, const int* in_sizes, int n_in,
                              void* d_out, int out_size, void* d_ws, size_t ws_size,
                              hipStream_t stream) {
    const float* x      = (const float*)d_in[0];  // [B,N,E]
    const float* qkv_w  = (const float*)d_in[1];  // [3E,E]
    const float* qkv_b  = (const float*)d_in[2];  // [3E]
    const float* proj_w = (const float*)d_in[3];  // [E,E]
    const float* proj_b = (const float*)d_in[4];  // [E]
    float* out = (float*)d_out;                   // [B,N,E]

    const size_t qkv_elems = (size_t)Bb * NH * Ns * DH;  // 2M floats each
    float* qs = (float*)d_ws;
    float* ks = qs + qkv_elems;
    float* vs = ks + qkv_elems;
    float* ao = vs + qkv_elems;                          // [B,N,E] attn output

    dim3 blk(256);
    dim3 g_qkv(Mrows / BM, (3 * Es) / BN);   // 128 x 12
    gemm_nt<0><<<g_qkv, blk, 0, stream>>>(x, qkv_w, qkv_b, qs, ks, vs);

    dim3 g_att((Bb * NH * Ns) / 256);        // 256 blocks
    attn_win<<<g_att, blk, 0, stream>>>(qs, ks, vs, ao);

    dim3 g_prj(Mrows / BM, Es / BN);         // 128 x 4
    gemm_nt<1><<<g_prj, blk, 0, stream>>>(ao, proj_w, proj_b, out, nullptr, nullptr);
}

// Round 2
// 171.381 us; speedup vs baseline: 1.5586x; 1.5586x over previous
//
#include <hip/hip_runtime.h>
#include <math.h>

// Problem constants
constexpr int Bb = 8;     // batch
constexpr int Ns = 1024;  // tokens (32x32)
constexpr int Es = 256;   // embed
constexpr int NH = 8;     // heads
constexpr int DH = 32;    // head dim
constexpr int Mrows = Bb * Ns;  // 8192

// GEMM tiling
#define BM 64
#define BN 64
#define BK 32
#define LDT 68   // padded stride (floats) for transposed LDS tiles; keeps 16B align

// C = A[M,K] @ W[Ncol,K]^T + bias, K = 256.
// MODE 0: QKV epilogue -> scatter (q*scale, k, v) into [B][H][N][DH] buffers.
// MODE 1: proj epilogue -> o0[row*Es + col].
template<int MODE>
__global__ __launch_bounds__(256)
void gemm_nt(const float* __restrict__ A, const float* __restrict__ W,
             const float* __restrict__ bias,
             float* __restrict__ o0, float* __restrict__ o1, float* __restrict__ o2)
{
    __shared__ float AsT[BK][LDT];
    __shared__ float WsT[BK][LDT];
    const int K = Es;
    int t = threadIdx.x;
    int m0 = blockIdx.x * BM;
    int j0 = blockIdx.y * BN;
    int ty = t >> 4, tx = t & 15;
    int lrow = t >> 3;          // 0..31
    int lc = (t & 7) << 2;      // 0,4,..,28
    float acc[4][4] = {};
    for (int k0 = 0; k0 < K; k0 += BK) {
        float4 a0 = *(const float4*)(A + (size_t)(m0 + lrow) * K + k0 + lc);
        float4 a1 = *(const float4*)(A + (size_t)(m0 + lrow + 32) * K + k0 + lc);
        float4 w0 = *(const float4*)(W + (size_t)(j0 + lrow) * K + k0 + lc);
        float4 w1 = *(const float4*)(W + (size_t)(j0 + lrow + 32) * K + k0 + lc);
        __syncthreads();  // protect previous iteration's LDS reads
        AsT[lc+0][lrow] = a0.x; AsT[lc+1][lrow] = a0.y;
        AsT[lc+2][lrow] = a0.z; AsT[lc+3][lrow] = a0.w;
        AsT[lc+0][lrow+32] = a1.x; AsT[lc+1][lrow+32] = a1.y;
        AsT[lc+2][lrow+32] = a1.z; AsT[lc+3][lrow+32] = a1.w;
        WsT[lc+0][lrow] = w0.x; WsT[lc+1][lrow] = w0.y;
        WsT[lc+2][lrow] = w0.z; WsT[lc+3][lrow] = w0.w;
        WsT[lc+0][lrow+32] = w1.x; WsT[lc+1][lrow+32] = w1.y;
        WsT[lc+2][lrow+32] = w1.z; WsT[lc+3][lrow+32] = w1.w;
        __syncthreads();
        #pragma unroll
        for (int kk = 0; kk < BK; kk++) {
            float4 ar = *(const float4*)&AsT[kk][ty << 2];  // ds_read_b128
            float4 wr = *(const float4*)&WsT[kk][tx << 2];
            float av[4] = {ar.x, ar.y, ar.z, ar.w};
            float wv[4] = {wr.x, wr.y, wr.z, wr.w};
            #pragma unroll
            for (int i = 0; i < 4; i++)
                #pragma unroll
                for (int j = 0; j < 4; j++)
                    acc[i][j] = fmaf(av[i], wv[j], acc[i][j]);
        }
    }
    #pragma unroll
    for (int i = 0; i < 4; i++) {
        int row = m0 + (ty << 2) + i;
        #pragma unroll
        for (int j = 0; j < 4; j++) {
            int col = j0 + (tx << 2) + j;
            float val = acc[i][j] + bias[col];
            if (MODE == 0) {
                int part = col >> 8;           // 0:q 1:k 2:v
                int head = (col >> 5) & 7;
                int d = col & 31;
                int b = row >> 10;
                int n = row & 1023;
                size_t idx = (((size_t)(b * NH + head)) * Ns + n) * DH + d;
                if (part == 0)      o0[idx] = val * 0.0625f;  // scale = E^-0.5
                else if (part == 1) o1[idx] = val;
                else                o2[idx] = val;
            } else {
                o0[(size_t)row * Es + col] = val;
            }
        }
    }
}

// ---------------------------------------------------------------------------
// Attention v2: one block per (b*NH+h, hq). 256 threads.
// 8 threads per query (32 queries = one grid row). Window: 7 rows x 11 cols.
// K/V/Q staged in LDS with padded row stride 36 (breaks stride-32 bank aliasing).
// ---------------------------------------------------------------------------
#define KVP 36          // padded row stride (floats) for Ks/Vs/Qs
#define SCP 84          // padded stride for score tile (84 mod 32 = 20, coprime-ish)

__global__ __launch_bounds__(256)
void attn_win2(const float* __restrict__ q, const float* __restrict__ k,
               const float* __restrict__ v, float* __restrict__ out)
{
    __shared__ float Qs[32 * KVP];
    __shared__ float Ks[7 * 32 * KVP];
    __shared__ float Vs[7 * 32 * KVP];
    __shared__ float Sc[32 * SCP];

    const int blk = blockIdx.x;          // 0..2047
    const int hq  = blk & 31;
    const int bh  = blk >> 5;            // b*NH + h
    const int t   = threadIdx.x;

    const int sr   = t >> 3;             // staging row 0..31
    const int scol = (t & 7) << 2;       // staging col 0,4,..,28

    // Stage Q row (already scaled by 1/16 in qkv gemm)
    {
        const float4 qv = *(const float4*)(q + ((size_t)bh * Ns + hq * 32 + sr) * DH + scol);
        *(float4*)&Qs[sr * KVP + scol] = qv;
    }
    // Stage 7 K/V rows (zero-fill invalid rows of V; K guarded at use)
    #pragma unroll
    for (int r = 0; r < 7; r++) {
        int hh = hq - 3 + r;
        if (hh >= 0 && hh < 32) {
            const float4 kv = *(const float4*)(k + ((size_t)bh * Ns + hh * 32 + sr) * DH + scol);
            const float4 vv = *(const float4*)(v + ((size_t)bh * Ns + hh * 32 + sr) * DH + scol);
            *(float4*)&Ks[(r * 32 + sr) * KVP + scol] = kv;
            *(float4*)&Vs[(r * 32 + sr) * KVP + scol] = vv;
        } else {
            *(float4*)&Vs[(r * 32 + sr) * KVP + scol] = make_float4(0.f, 0.f, 0.f, 0.f);
        }
    }
    __syncthreads();

    const int wq    = t >> 3;            // query owned by this 8-lane group
    const int lane8 = t & 7;

    // q into registers
    float4 qr[8];
    {
        const float* qrow = &Qs[wq * KVP];
        #pragma unroll
        for (int i = 0; i < 8; i++) qr[i] = *(const float4*)(qrow + i * 4);
    }

    // ---- scores: slots s = lane8, lane8+8, ... < 77 ----
    float smax = -INFINITY;
    for (unsigned s = lane8; s < 77u; s += 8u) {
        unsigned dr = s / 11u, dc = s % 11u;
        int hh = hq - 3 + (int)dr;
        int ww = wq - 5 + (int)dc;
        float sc = -INFINITY;
        if (hh >= 0 && hh < 32 && ww >= 0 && ww < 32) {
            const float* krow = &Ks[((int)dr * 32 + ww) * KVP];
            float acc = 0.f;
            #pragma unroll
            for (int i = 0; i < 8; i++) {
                float4 kv = *(const float4*)(krow + i * 4);
                acc = fmaf(qr[i].x, kv.x, acc); acc = fmaf(qr[i].y, kv.y, acc);
                acc = fmaf(qr[i].z, kv.z, acc); acc = fmaf(qr[i].w, kv.w, acc);
            }
            sc = acc;
        }
        Sc[wq * SCP + s] = sc;
        smax = fmaxf(smax, sc);
    }
    // 8-lane max (groups are contiguous lanes within one wave)
    #pragma unroll
    for (int m = 1; m < 8; m <<= 1) smax = fmaxf(smax, __shfl_xor(smax, m));

    float lsum = 0.f;
    for (unsigned s = lane8; s < 77u; s += 8u) {
        float p = __expf(Sc[wq * SCP + s] - smax);  // -inf -> 0
        Sc[wq * SCP + s] = p;
        lsum += p;
    }
    #pragma unroll
    for (int m = 1; m < 8; m <<= 1) lsum += __shfl_xor(lsum, m);
    const float inv = 1.f / lsum;
    // Sc[wq][*] written and read only by this 8-lane group (same wave): no barrier.

    // ---- PV: lane owns dims d0..d0+3 ----
    const int d0 = lane8 << 2;
    float4 acc = make_float4(0.f, 0.f, 0.f, 0.f);
    int sidx = 0;
    #pragma unroll
    for (int dr = 0; dr < 7; dr++) {
        #pragma unroll
        for (int dc = 0; dc < 11; dc++, sidx++) {
            float p = Sc[wq * SCP + sidx];           // 0 for invalid slots
            int ww = wq - 5 + dc;
            int wwc = ww < 0 ? 0 : (ww > 31 ? 31 : ww);
            float4 vv = *(const float4*)&Vs[(dr * 32 + wwc) * KVP + d0];
            acc.x = fmaf(p, vv.x, acc.x);
            acc.y = fmaf(p, vv.y, acc.y);
            acc.z = fmaf(p, vv.z, acc.z);
            acc.w = fmaf(p, vv.w, acc.w);
        }
    }
    acc.x *= inv; acc.y *= inv; acc.z *= inv; acc.w *= inv;

    const int b = bh >> 3, h = bh & 7;
    float* obase = out + ((size_t)(b * Ns + hq * 32 + wq)) * Es + h * DH + d0;
    *(float4*)obase = acc;
}

extern "C" void kernel_launch(void* const* d_in, const int* in_sizes, int n_in,
                              void* d_out, int out_size, void* d_ws, size_t ws_size,
                              hipStream_t stream) {
    const float* x      = (const float*)d_in[0];  // [B,N,E]
    const float* qkv_w  = (const float*)d_in[1];  // [3E,E]
    const float* qkv_b  = (const float*)d_in[2];  // [3E]
    const float* proj_w = (const float*)d_in[3];  // [E,E]
    const float* proj_b = (const float*)d_in[4];  // [E]
    float* out = (float*)d_out;                   // [B,N,E]

    const size_t qkv_elems = (size_t)Bb * NH * Ns * DH;  // 2M floats each
    float* qs = (float*)d_ws;
    float* ks = qs + qkv_elems;
    float* vs = ks + qkv_elems;
    float* ao = vs + qkv_elems;                          // [B,N,E] attn output

    dim3 blk(256);
    dim3 g_qkv(Mrows / BM, (3 * Es) / BN);   // 128 x 12
    gemm_nt<0><<<g_qkv, blk, 0, stream>>>(x, qkv_w, qkv_b, qs, ks, vs);

    dim3 g_att(Bb * NH * 32);                // 2048 blocks: (bh, hq)
    attn_win2<<<g_att, blk, 0, stream>>>(qs, ks, vs, ao);

    dim3 g_prj(Mrows / BM, Es / BN);         // 128 x 4
    gemm_nt<1><<<g_prj, blk, 0, stream>>>(ao, proj_w, proj_b, out, nullptr, nullptr);
}

// Round 3
// 121.773 us; speedup vs baseline: 2.1936x; 1.4074x over previous
//
#include <hip/hip_runtime.h>
#include <math.h>

// Problem constants
constexpr int Bb = 8;     // batch
constexpr int Ns = 1024;  // tokens (32x32)
constexpr int Es = 256;   // embed
constexpr int NH = 8;     // heads
constexpr int DH = 32;    // head dim
constexpr int Mrows = Bb * Ns;  // 8192

typedef __bf16 bf16x8 __attribute__((ext_vector_type(8)));
typedef float  f32x4  __attribute__((ext_vector_type(4)));

__device__ __forceinline__ unsigned short f2bf(float f) {
    union { float f; unsigned u; } c; c.f = f;
    unsigned r = (c.u + 0x7FFFu + ((c.u >> 16) & 1u)) >> 16;
    return (unsigned short)r;
}

// ---------------------------------------------------------------------------
// Cast pass: x, qkv_w, proj_w  fp32 -> bf16 (RNE), vectorized x4.
// ---------------------------------------------------------------------------
constexpr int NX = Mrows * Es;        // 2097152
constexpr int NQ = 3 * Es * Es;       // 196608
constexpr int NP = Es * Es;           // 65536

__global__ __launch_bounds__(256)
void cast_bf16(const float* __restrict__ x, const float* __restrict__ wq,
               const float* __restrict__ wp, unsigned short* __restrict__ xb,
               unsigned short* __restrict__ wqb, unsigned short* __restrict__ wpb)
{
    int i = (blockIdx.x * 256 + threadIdx.x) * 4;
    const float* src; unsigned short* dst;
    if (i < NX)            { src = x  + i;            dst = xb  + i; }
    else if (i < NX + NQ)  { src = wq + (i - NX);     dst = wqb + (i - NX); }
    else                   { src = wp + (i - NX - NQ); dst = wpb + (i - NX - NQ); }
    float4 f = *(const float4*)src;
    ushort4 u;
    u.x = f2bf(f.x); u.y = f2bf(f.y); u.z = f2bf(f.z); u.w = f2bf(f.w);
    *(ushort4*)dst = u;
}

// ---------------------------------------------------------------------------
// bf16 MFMA GEMM: C = A[M,256] @ W[N,256]^T + bias, fp32 accum/output.
// 64x64 tile, 256 thr (4 waves), wave = 2x2 tiles of 16x16x32 MFMA.
// MODE 0: QKV epilogue scatter (q*1/16, k, v) fp32. MODE 1: proj -> o0 fp32.
// ---------------------------------------------------------------------------
template<int MODE>
__global__ __launch_bounds__(256)
void gemm_mfma(const unsigned short* __restrict__ A, const unsigned short* __restrict__ W,
               const float* __restrict__ bias,
               float* __restrict__ o0, float* __restrict__ o1, float* __restrict__ o2)
{
    __shared__ unsigned short As[64 * 32];   // 4 KB, packed rows of 32 bf16
    __shared__ unsigned short Ws[64 * 32];

    const int t = threadIdx.x;
    const int m0 = blockIdx.x * 64;
    const int j0 = blockIdx.y * 64;

    // staging: thread -> (row = t>>2, 8-elem chunk = (t&3)*8)
    const int srow = t >> 2;
    const int scol = (t & 3) * 8;

    const int lane = t & 63;
    const int wave = t >> 6;
    const int wm = (wave & 1) * 32;   // wave quadrant rows
    const int wn = (wave >> 1) * 32;  // wave quadrant cols
    const int fm = lane & 15;         // fragment row/col within 16
    const int fq = lane >> 4;         // quad 0..3

    f32x4 acc[2][2];
    #pragma unroll
    for (int i = 0; i < 2; i++)
        #pragma unroll
        for (int j = 0; j < 2; j++)
            acc[i][j] = (f32x4){0.f, 0.f, 0.f, 0.f};

    for (int k0 = 0; k0 < Es; k0 += 32) {
        const uint4 av = *(const uint4*)(A + (size_t)(m0 + srow) * Es + k0 + scol);
        const uint4 wv = *(const uint4*)(W + (size_t)(j0 + srow) * Es + k0 + scol);
        __syncthreads();   // previous tile fully consumed
        *(uint4*)&As[srow * 32 + scol] = av;
        *(uint4*)&Ws[srow * 32 + scol] = wv;
        __syncthreads();
        // fragments: lane holds [row = base + (l&15)][k = quad*8 .. +7]
        bf16x8 a0 = *(const bf16x8*)&As[(wm +      fm) * 32 + fq * 8];
        bf16x8 a1 = *(const bf16x8*)&As[(wm + 16 + fm) * 32 + fq * 8];
        bf16x8 b0 = *(const bf16x8*)&Ws[(wn +      fm) * 32 + fq * 8];
        bf16x8 b1 = *(const bf16x8*)&Ws[(wn + 16 + fm) * 32 + fq * 8];
        acc[0][0] = __builtin_amdgcn_mfma_f32_16x16x32_bf16(a0, b0, acc[0][0], 0, 0, 0);
        acc[0][1] = __builtin_amdgcn_mfma_f32_16x16x32_bf16(a0, b1, acc[0][1], 0, 0, 0);
        acc[1][0] = __builtin_amdgcn_mfma_f32_16x16x32_bf16(a1, b0, acc[1][0], 0, 0, 0);
        acc[1][1] = __builtin_amdgcn_mfma_f32_16x16x32_bf16(a1, b1, acc[1][1], 0, 0, 0);
    }

    // C/D mapping (m89-verified): col = lane&15, row = quad*4 + reg
    #pragma unroll
    for (int mt = 0; mt < 2; mt++) {
        #pragma unroll
        for (int nt = 0; nt < 2; nt++) {
            #pragma unroll
            for (int r = 0; r < 4; r++) {
                int row = m0 + wm + mt * 16 + fq * 4 + r;
                int col = j0 + wn + nt * 16 + fm;
                float val = acc[mt][nt][r] + bias[col];
                if (MODE == 0) {
                    int part = col >> 8;           // 0:q 1:k 2:v
                    int head = (col >> 5) & 7;
                    int d = col & 31;
                    int b = row >> 10;
                    int n = row & 1023;
                    size_t idx = (((size_t)(b * NH + head)) * Ns + n) * DH + d;
                    if (part == 0)      o0[idx] = val * 0.0625f;  // E^-0.5
                    else if (part == 1) o1[idx] = val;
                    else                o2[idx] = val;
                } else {
                    o0[(size_t)row * Es + col] = val;
                }
            }
        }
    }
}

// ---------------------------------------------------------------------------
// Attention: one block per (b*NH+h, hq). 256 threads, 8 threads per query.
// Window 7x11. Writes ao in bf16 for the proj GEMM.
// ---------------------------------------------------------------------------
#define KVP 36
#define SCP 84

__global__ __launch_bounds__(256)
void attn_win2(const float* __restrict__ q, const float* __restrict__ k,
               const float* __restrict__ v, unsigned short* __restrict__ out)
{
    __shared__ float Qs[32 * KVP];
    __shared__ float Ks[7 * 32 * KVP];
    __shared__ float Vs[7 * 32 * KVP];
    __shared__ float Sc[32 * SCP];

    const int blk = blockIdx.x;          // 0..2047
    const int hq  = blk & 31;
    const int bh  = blk >> 5;            // b*NH + h
    const int t   = threadIdx.x;

    const int sr   = t >> 3;
    const int scol = (t & 7) << 2;

    {
        const float4 qv = *(const float4*)(q + ((size_t)bh * Ns + hq * 32 + sr) * DH + scol);
        *(float4*)&Qs[sr * KVP + scol] = qv;
    }
    #pragma unroll
    for (int r = 0; r < 7; r++) {
        int hh = hq - 3 + r;
        if (hh >= 0 && hh < 32) {
            const float4 kv = *(const float4*)(k + ((size_t)bh * Ns + hh * 32 + sr) * DH + scol);
            const float4 vv = *(const float4*)(v + ((size_t)bh * Ns + hh * 32 + sr) * DH + scol);
            *(float4*)&Ks[(r * 32 + sr) * KVP + scol] = kv;
            *(float4*)&Vs[(r * 32 + sr) * KVP + scol] = vv;
        } else {
            *(float4*)&Vs[(r * 32 + sr) * KVP + scol] = make_float4(0.f, 0.f, 0.f, 0.f);
        }
    }
    __syncthreads();

    const int wq    = t >> 3;
    const int lane8 = t & 7;

    float4 qr[8];
    {
        const float* qrow = &Qs[wq * KVP];
        #pragma unroll
        for (int i = 0; i < 8; i++) qr[i] = *(const float4*)(qrow + i * 4);
    }

    float smax = -INFINITY;
    for (unsigned s = lane8; s < 77u; s += 8u) {
        unsigned dr = s / 11u, dc = s % 11u;
        int hh = hq - 3 + (int)dr;
        int ww = wq - 5 + (int)dc;
        float sc = -INFINITY;
        if (hh >= 0 && hh < 32 && ww >= 0 && ww < 32) {
            const float* krow = &Ks[((int)dr * 32 + ww) * KVP];
            float acc = 0.f;
            #pragma unroll
            for (int i = 0; i < 8; i++) {
                float4 kv = *(const float4*)(krow + i * 4);
                acc = fmaf(qr[i].x, kv.x, acc); acc = fmaf(qr[i].y, kv.y, acc);
                acc = fmaf(qr[i].z, kv.z, acc); acc = fmaf(qr[i].w, kv.w, acc);
            }
            sc = acc;
        }
        Sc[wq * SCP + s] = sc;
        smax = fmaxf(smax, sc);
    }
    #pragma unroll
    for (int m = 1; m < 8; m <<= 1) smax = fmaxf(smax, __shfl_xor(smax, m));

    float lsum = 0.f;
    for (unsigned s = lane8; s < 77u; s += 8u) {
        float p = __expf(Sc[wq * SCP + s] - smax);
        Sc[wq * SCP + s] = p;
        lsum += p;
    }
    #pragma unroll
    for (int m = 1; m < 8; m <<= 1) lsum += __shfl_xor(lsum, m);
    const float inv = 1.f / lsum;

    const int d0 = lane8 << 2;
    float4 acc = make_float4(0.f, 0.f, 0.f, 0.f);
    int sidx = 0;
    #pragma unroll
    for (int dr = 0; dr < 7; dr++) {
        #pragma unroll
        for (int dc = 0; dc < 11; dc++, sidx++) {
            float p = Sc[wq * SCP + sidx];
            int ww = wq - 5 + dc;
            int wwc = ww < 0 ? 0 : (ww > 31 ? 31 : ww);
            float4 vv = *(const float4*)&Vs[(dr * 32 + wwc) * KVP + d0];
            acc.x = fmaf(p, vv.x, acc.x);
            acc.y = fmaf(p, vv.y, acc.y);
            acc.z = fmaf(p, vv.z, acc.z);
            acc.w = fmaf(p, vv.w, acc.w);
        }
    }
    const int b = bh >> 3, h = bh & 7;
    unsigned short* obase = out + ((size_t)(b * Ns + hq * 32 + wq)) * Es + h * DH + d0;
    ushort4 o;
    o.x = f2bf(acc.x * inv); o.y = f2bf(acc.y * inv);
    o.z = f2bf(acc.z * inv); o.w = f2bf(acc.w * inv);
    *(ushort4*)obase = o;
}

extern "C" void kernel_launch(void* const* d_in, const int* in_sizes, int n_in,
                              void* d_out, int out_size, void* d_ws, size_t ws_size,
                              hipStream_t stream) {
    const float* x      = (const float*)d_in[0];  // [B,N,E]
    const float* qkv_w  = (const float*)d_in[1];  // [3E,E]
    const float* qkv_b  = (const float*)d_in[2];  // [3E]
    const float* proj_w = (const float*)d_in[3];  // [E,E]
    const float* proj_b = (const float*)d_in[4];  // [E]
    float* out = (float*)d_out;                   // [B,N,E]

    // workspace layout (16B-aligned slabs)
    float* qs = (float*)d_ws;                     // 2M fp32
    float* ks = qs + NX;
    float* vs = ks + NX;
    unsigned short* xb  = (unsigned short*)(vs + NX);  // 2M bf16
    unsigned short* wqb = xb + NX;                     // 196608 bf16
    unsigned short* wpb = wqb + NQ;                    // 65536 bf16
    unsigned short* aob = wpb + NP;                    // 2M bf16

    dim3 blk(256);

    cast_bf16<<<dim3((NX + NQ + NP) / 4 / 256), blk, 0, stream>>>(x, qkv_w, proj_w, xb, wqb, wpb);

    dim3 g_qkv(Mrows / 64, (3 * Es) / 64);   // 128 x 12
    gemm_mfma<0><<<g_qkv, blk, 0, stream>>>(xb, wqb, qkv_b, qs, ks, vs);

    dim3 g_att(Bb * NH * 32);                // 2048 blocks
    attn_win2<<<g_att, blk, 0, stream>>>(qs, ks, vs, aob);

    dim3 g_prj(Mrows / 64, Es / 64);         // 128 x 4
    gemm_mfma<1><<<g_prj, blk, 0, stream>>>(aob, wpb, proj_b, out, nullptr, nullptr);
}

// Round 4
// 103.884 us; speedup vs baseline: 2.5713x; 1.1722x over previous
//
#include <hip/hip_runtime.h>
#include <math.h>

// Problem constants
constexpr int Bb = 8;     // batch
constexpr int Ns = 1024;  // tokens (32x32)
constexpr int Es = 256;   // embed
constexpr int NH = 8;     // heads
constexpr int DH = 32;    // head dim
constexpr int Mrows = Bb * Ns;  // 8192

constexpr int NX = Mrows * Es;        // 2097152 (also = Bb*NH*Ns*DH)
constexpr int NQ = 3 * Es * Es;       // 196608
constexpr int NP = Es * Es;           // 65536

typedef __bf16 bf16x8 __attribute__((ext_vector_type(8)));
typedef float  f32x4  __attribute__((ext_vector_type(4)));
union U4B8 { uint4 u; bf16x8 b; };

__device__ __forceinline__ unsigned short f2bf(float f) {
    union { float f; unsigned u; } c; c.f = f;
    unsigned r = (c.u + 0x7FFFu + ((c.u >> 16) & 1u)) >> 16;
    return (unsigned short)r;
}
__device__ __forceinline__ float bf2f(unsigned short h) {
    union { unsigned u; float f; } c; c.u = ((unsigned)h) << 16;
    return c.f;
}

// ---------------------------------------------------------------------------
// Cast pass: x, qkv_w, proj_w  fp32 -> bf16 (RNE), vectorized x4.
// ---------------------------------------------------------------------------
__global__ __launch_bounds__(256)
void cast_bf16(const float* __restrict__ x, const float* __restrict__ wq,
               const float* __restrict__ wp, unsigned short* __restrict__ xb,
               unsigned short* __restrict__ wqb, unsigned short* __restrict__ wpb)
{
    int i = (blockIdx.x * 256 + threadIdx.x) * 4;
    const float* src; unsigned short* dst;
    if (i < NX)            { src = x  + i;             dst = xb  + i; }
    else if (i < NX + NQ)  { src = wq + (i - NX);      dst = wqb + (i - NX); }
    else                   { src = wp + (i - NX - NQ); dst = wpb + (i - NX - NQ); }
    float4 f = *(const float4*)src;
    ushort4 u;
    u.x = f2bf(f.x); u.y = f2bf(f.y); u.z = f2bf(f.z); u.w = f2bf(f.w);
    *(ushort4*)dst = u;
}

// ---------------------------------------------------------------------------
// bf16 MFMA GEMM: C = A[M,256] @ W[N,256]^T + bias. 64x64 tile, BK=64.
// 256 thr (4 waves), wave = 2x2 tiles of 16x16x32 MFMA, 8 MFMA per barrier pair.
// MODE 0 (qkv): q*1/16 -> qo bf16 [bh][n][d]; k -> ko bf16 [bh][n][d];
//               v -> vto bf16 [bh][d][n] (transposed for PV B-operand).
// MODE 1 (proj): fp32 out [row][col].
// ---------------------------------------------------------------------------
#define GLD 72   // LDS row stride in bf16 (144 B = 16B-aligned, breaks 128B aliasing)

template<int MODE>
__global__ __launch_bounds__(256)
void gemm_mfma(const unsigned short* __restrict__ A, const unsigned short* __restrict__ W,
               const float* __restrict__ bias,
               unsigned short* __restrict__ qo, unsigned short* __restrict__ ko,
               unsigned short* __restrict__ vto, float* __restrict__ fo)
{
    __shared__ unsigned short As[64 * GLD];
    __shared__ unsigned short Ws[64 * GLD];

    const int t = threadIdx.x;
    const int m0 = blockIdx.x * 64;
    const int j0 = blockIdx.y * 64;

    const int srow = t >> 2;          // 0..63
    const int scol = (t & 3) * 16;    // 0,16,32,48

    const int lane = t & 63;
    const int wave = t >> 6;
    const int wm = (wave & 1) * 32;
    const int wn = (wave >> 1) * 32;
    const int fm = lane & 15;
    const int fq = lane >> 4;

    f32x4 acc[2][2];
    #pragma unroll
    for (int i = 0; i < 2; i++)
        #pragma unroll
        for (int j = 0; j < 2; j++)
            acc[i][j] = (f32x4){0.f, 0.f, 0.f, 0.f};

    for (int k0 = 0; k0 < Es; k0 += 64) {
        const uint4 a0 = *(const uint4*)(A + (size_t)(m0 + srow) * Es + k0 + scol);
        const uint4 a1 = *(const uint4*)(A + (size_t)(m0 + srow) * Es + k0 + scol + 8);
        const uint4 w0 = *(const uint4*)(W + (size_t)(j0 + srow) * Es + k0 + scol);
        const uint4 w1 = *(const uint4*)(W + (size_t)(j0 + srow) * Es + k0 + scol + 8);
        __syncthreads();
        *(uint4*)&As[srow * GLD + scol] = a0;
        *(uint4*)&As[srow * GLD + scol + 8] = a1;
        *(uint4*)&Ws[srow * GLD + scol] = w0;
        *(uint4*)&Ws[srow * GLD + scol + 8] = w1;
        __syncthreads();
        #pragma unroll
        for (int ks = 0; ks < 64; ks += 32) {
            U4B8 af0, af1, bf0, bf1;
            af0.u = *(const uint4*)&As[(wm +      fm) * GLD + ks + fq * 8];
            af1.u = *(const uint4*)&As[(wm + 16 + fm) * GLD + ks + fq * 8];
            bf0.u = *(const uint4*)&Ws[(wn +      fm) * GLD + ks + fq * 8];
            bf1.u = *(const uint4*)&Ws[(wn + 16 + fm) * GLD + ks + fq * 8];
            acc[0][0] = __builtin_amdgcn_mfma_f32_16x16x32_bf16(af0.b, bf0.b, acc[0][0], 0, 0, 0);
            acc[0][1] = __builtin_amdgcn_mfma_f32_16x16x32_bf16(af0.b, bf1.b, acc[0][1], 0, 0, 0);
            acc[1][0] = __builtin_amdgcn_mfma_f32_16x16x32_bf16(af1.b, bf0.b, acc[1][0], 0, 0, 0);
            acc[1][1] = __builtin_amdgcn_mfma_f32_16x16x32_bf16(af1.b, bf1.b, acc[1][1], 0, 0, 0);
        }
    }

    // C/D mapping: col = lane&15, row = quad*4 + reg
    #pragma unroll
    for (int mt = 0; mt < 2; mt++) {
        #pragma unroll
        for (int nt = 0; nt < 2; nt++) {
            #pragma unroll
            for (int r = 0; r < 4; r++) {
                int row = m0 + wm + mt * 16 + fq * 4 + r;
                int col = j0 + wn + nt * 16 + fm;
                float val = acc[mt][nt][r] + bias[col];
                if (MODE == 0) {
                    int part = col >> 8;           // 0:q 1:k 2:v
                    int head = (col >> 5) & 7;
                    int d = col & 31;
                    int b = row >> 10;
                    int n = row & 1023;
                    int bh = b * NH + head;
                    if (part == 0)
                        qo[((size_t)bh * Ns + n) * DH + d] = f2bf(val * 0.0625f);
                    else if (part == 1)
                        ko[((size_t)bh * Ns + n) * DH + d] = f2bf(val);
                    else
                        vto[((size_t)bh * DH + d) * Ns + n] = f2bf(val);
                } else {
                    fo[(size_t)row * Es + col] = val;
                }
            }
        }
    }
}

// ---------------------------------------------------------------------------
// MFMA attention. One block per (bh, hq), 256 thr (4 waves).
// Keys = 224 contiguous tokens [n0c, n0c+224); window mask from abs coords.
// S = Q.K^T: 28 MFMAs (dh=32 = single K-step). Softmax rows via LDS.
// PV: 28 MFMAs, V^T fragments prefetched from global (vt layout).
// ---------------------------------------------------------------------------
#define SST 228   // S row stride (floats)
#define PST 232   // P row stride (bf16); 464B rows, 16B-aligned

__global__ __launch_bounds__(256)
void attn_mfma(const unsigned short* __restrict__ qb, const unsigned short* __restrict__ kb,
               const unsigned short* __restrict__ vtb, unsigned short* __restrict__ aob)
{
    __shared__ float S[32 * SST];
    __shared__ unsigned short Pb[32 * PST];
    __shared__ float Linv[32];

    const int blk = blockIdx.x;          // 0..2047
    const int hq  = blk & 31;
    const int bh  = blk >> 5;
    const int t   = threadIdx.x;
    const int lane = t & 63;
    const int w    = t >> 6;
    const int fm = lane & 15;
    const int fq = lane >> 4;

    int n0c = (hq - 3) * 32;
    n0c = n0c < 0 ? 0 : (n0c > Ns - 224 ? Ns - 224 : n0c);

    const int qbase = (w & 1) * 16;      // S & PV q-tile
    const int sel   = w >> 1;            // S key tiles: sel, sel+2, ...
    const int dbase = (w >> 1) * 16;     // PV dim-tile

    // ---- V^T fragment prefetch (B-operand: n=dim, k=key) ----
    const unsigned short* vrow = vtb + ((size_t)bh * DH + dbase + fm) * Ns;
    uint4 vpre[7];
    #pragma unroll
    for (int i = 0; i < 7; i++)
        vpre[i] = *(const uint4*)(vrow + n0c + i * 32 + fq * 8);

    // ---- Q fragment (A-operand: m=query, k=dim) ----
    U4B8 qa;
    qa.u = *(const uint4*)(qb + ((size_t)bh * Ns + hq * 32 + qbase + fm) * DH + fq * 8);

    // ---- S = Q.K^T ----
    #pragma unroll
    for (int i = 0; i < 7; i++) {
        int kt = sel + 2 * i;
        U4B8 kf;
        kf.u = *(const uint4*)(kb + ((size_t)bh * Ns + n0c + kt * 16 + fm) * DH + fq * 8);
        f32x4 s = __builtin_amdgcn_mfma_f32_16x16x32_bf16(qa.b, kf.b, (f32x4){0.f,0.f,0.f,0.f}, 0, 0, 0);
        #pragma unroll
        for (int r = 0; r < 4; r++)
            S[(qbase + fq * 4 + r) * SST + kt * 16 + fm] = s[r];
    }
    __syncthreads();

    // ---- masked softmax: 8 lanes per query, 28 keys each ----
    const int sq = t >> 3;               // query column wq (= grid col)
    const int l8 = t & 7;
    float sv[28];
    float smax = -INFINITY;
    #pragma unroll
    for (int i = 0; i < 28; i++) {
        int j = l8 + 8 * i;
        int g = n0c + j;
        int gh = g >> 5, gw = g & 31;
        int dh_ = gh - hq, dw_ = gw - sq;
        bool ok = (dh_ >= -3) && (dh_ <= 3) && (dw_ >= -5) && (dw_ <= 5);
        float x = ok ? S[sq * SST + j] : -INFINITY;
        sv[i] = x;
        smax = fmaxf(smax, x);
    }
    #pragma unroll
    for (int m = 1; m < 8; m <<= 1) smax = fmaxf(smax, __shfl_xor(smax, m));

    float lsum = 0.f;
    #pragma unroll
    for (int i = 0; i < 28; i++) {
        float p = __expf(sv[i] - smax);   // -inf -> 0
        unsigned short pu = f2bf(p);
        Pb[sq * PST + l8 + 8 * i] = pu;
        lsum += bf2f(pu);                 // sum the rounded values
    }
    #pragma unroll
    for (int m = 1; m < 8; m <<= 1) lsum += __shfl_xor(lsum, m);
    if (l8 == 0) Linv[sq] = 1.f / lsum;
    __syncthreads();

    // ---- O = P.V ----
    f32x4 acc = (f32x4){0.f, 0.f, 0.f, 0.f};
    #pragma unroll
    for (int i = 0; i < 7; i++) {
        U4B8 pa, vb;
        pa.u = *(const uint4*)&Pb[(qbase + fm) * PST + i * 32 + fq * 8];
        vb.u = vpre[i];
        acc = __builtin_amdgcn_mfma_f32_16x16x32_bf16(pa.b, vb.b, acc, 0, 0, 0);
    }

    const int b = bh >> 3, h = bh & 7;
    #pragma unroll
    for (int r = 0; r < 4; r++) {
        int qq = qbase + fq * 4 + r;
        float o = acc[r] * Linv[qq];
        aob[((size_t)(b * Ns) + hq * 32 + qq) * Es + h * DH + dbase + fm] = f2bf(o);
    }
}

extern "C" void kernel_launch(void* const* d_in, const int* in_sizes, int n_in,
                              void* d_out, int out_size, void* d_ws, size_t ws_size,
                              hipStream_t stream) {
    const float* x      = (const float*)d_in[0];  // [B,N,E]
    const float* qkv_w  = (const float*)d_in[1];  // [3E,E]
    const float* qkv_b  = (const float*)d_in[2];  // [3E]
    const float* proj_w = (const float*)d_in[3];  // [E,E]
    const float* proj_b = (const float*)d_in[4];  // [E]
    float* out = (float*)d_out;                   // [B,N,E]

    unsigned short* xb  = (unsigned short*)d_ws;  // NX bf16
    unsigned short* wqb = xb + NX;                // NQ
    unsigned short* wpb = wqb + NQ;               // NP
    unsigned short* qb  = wpb + NP;               // NX (q, scaled, [bh][n][d])
    unsigned short* kb  = qb + NX;                // NX ([bh][n][d])
    unsigned short* vtb = kb + NX;                // NX ([bh][d][n])
    unsigned short* aob = vtb + NX;               // NX ([b][n][e])

    dim3 blk(256);

    cast_bf16<<<dim3((NX + NQ + NP) / 4 / 256), blk, 0, stream>>>(x, qkv_w, proj_w, xb, wqb, wpb);

    dim3 g_qkv(Mrows / 64, (3 * Es) / 64);   // 128 x 12
    gemm_mfma<0><<<g_qkv, blk, 0, stream>>>(xb, wqb, qkv_b, qb, kb, vtb, nullptr);

    dim3 g_att(Bb * NH * 32);                // 2048 blocks
    attn_mfma<<<g_att, blk, 0, stream>>>(qb, kb, vtb, aob);

    dim3 g_prj(Mrows / 64, Es / 64);         // 128 x 4
    gemm_mfma<1><<<g_prj, blk, 0, stream>>>(aob, wpb, proj_b, nullptr, nullptr, nullptr, out);
}